// Round 2
// baseline (147.862 us; speedup 1.0000x reference)
//
#include <hip/hip_runtime.h>
#include <hip/hip_bf16.h>
#include <stdint.h>

#define S_LEN 2048
#define D_DIM 1024
#define P_DIM 256
#define NQ_   8192
#define M_TOT 16384  // B*S

#define BM 64
#define BN 256
#define BK 64
#define CAP 32       // max span-endpoints per H row (lambda=2, P(>32)~1e-26)
#define HS  260      // padded f32 row stride for H tile in LDS (16B-aligned, bank-spread)

typedef __attribute__((ext_vector_type(4))) float  f32x4;
typedef __attribute__((ext_vector_type(8))) __bf16 bf16x8;

__device__ __forceinline__ void async16(const void* g, void* l) {
    __builtin_amdgcn_global_load_lds(
        (const __attribute__((address_space(1))) uint32_t*)g,
        (__attribute__((address_space(3))) uint32_t*)l, 16, 0, 0);
}

// ---------------- Kernel 0: W [1024][256] f32 -> WT [256][1024] bf16 ----------
// Also zeroes the 16384-entry row-bucket counters (first 16 blocks).
__global__ __launch_bounds__(1024) void wt_kernel(const float* __restrict__ W,
                                                  __bf16* __restrict__ WT,
                                                  int* __restrict__ cnt) {
    __shared__ __bf16 tile[32][33];
    const int k0 = blockIdx.x * 32;
    const int n0 = blockIdx.y * 32;
    const int tx = threadIdx.x, ty = threadIdx.y;
    const int g = (blockIdx.y * gridDim.x + blockIdx.x) * 1024 + ty * 32 + tx;
    if (g < M_TOT) cnt[g] = 0;
    tile[ty][tx] = (__bf16)W[(k0 + ty) * P_DIM + (n0 + tx)];
    __syncthreads();
    WT[(n0 + ty) * D_DIM + (k0 + tx)] = tile[tx][ty];
}

// ---------------- Kernel 1: inverted span index + invalid-span zeroing --------
// For each valid (q,set): endpoint rows get an entry (q<<2)|(set<<1)|half.
// Each dest slot in `out` is owned by exactly one entry -> atomic order moot.
// Invalid (q,set): whole wave zeroes the 2 KB span via ballot loop.
__global__ __launch_bounds__(256) void index_zero(const int* __restrict__ s1,
                                                  const int* __restrict__ e1,
                                                  const int* __restrict__ s2,
                                                  const int* __restrict__ e2,
                                                  const int* __restrict__ qb,
                                                  int* __restrict__ cnt,
                                                  int* __restrict__ bucket,
                                                  float* __restrict__ out) {
    const int q    = blockIdx.x * 256 + threadIdx.x;
    const int lane = threadIdx.x & 63;
    const int bqw  = blockIdx.x * 256 + (threadIdx.x & ~63);  // wave's first q
    const int b    = qb[q];
    const float4 z = make_float4(0.f, 0.f, 0.f, 0.f);
    #pragma unroll
    for (int set = 0; set < 2; ++set) {
        const int s = set ? s2[q] : s1[q];
        const int e = set ? e2[q] : e1[q];
        if (e >= s) {
            int r = b * S_LEN + s;
            int k = atomicAdd(&cnt[r], 1); if (k < CAP) bucket[r * CAP + k] = (q << 2) | (set << 1);
            r = b * S_LEN + e;
            k = atomicAdd(&cnt[r], 1);     if (k < CAP) bucket[r * CAP + k] = (q << 2) | (set << 1) | 1;
        }
        unsigned long long mask = __ballot(e < s);
        while (mask) {
            const int j = __ffsll(mask) - 1;
            mask &= mask - 1;
            const int qz = bqw + j;
            float4* dst = (float4*)(out + (size_t)set * (NQ_ * 512) + (size_t)qz * 512);
            dst[lane]      = z;
            dst[lane + 64] = z;
        }
    }
}

// ---------------- Kernel 2: H = A @ W + b, fused span-scatter epilogue --------
// m97-style async GEMM, BM=64: 256 thr = 4 waves; wave w -> cols [w*64,+64),
// ALL 64 rows: acc[4][4] = 32 MFMAs/K-step. Halves B-fragment LDS reads per
// FLOP vs BM=32 (LDS-throughput was the binding resource) and halves WT L2
// re-reads. Grid 256 = 1 block/CU; drains covered by issuing loads a full
// compute-phase (~900 cyc) ahead. Epilogue: stage tile (+bias) into the dead
// LDS, read row buckets, write each consumer's 1 KB slice straight to out.
__global__ __launch_bounds__(256, 1) void gemm_kernel(const float*  __restrict__ A,
                                                      const __bf16* __restrict__ WT,
                                                      const float*  __restrict__ bias,
                                                      const int*    __restrict__ cnt,
                                                      const int*    __restrict__ bucket,
                                                      float*        __restrict__ out) {
    __shared__ __align__(16) char smem[2 * BM * BK * 2 + 2 * BN * BK * 2];  // 80 KB
    __shared__ int s_cnt[64];
    __shared__ int s_off[65];
    __shared__ int elist[64 * CAP];

    const int tid = threadIdx.x;
    const int w   = tid >> 6;
    const int l   = tid & 63;
    const int lm  = l & 15;
    const int q   = l >> 4;

    const int m0 = blockIdx.x * BM;

    auto bufA = [&](int buf) -> __bf16* { return (__bf16*)smem + buf * (BM * BK); };
    auto bufB = [&](int buf) -> __bf16* { return (__bf16*)(smem + 2 * BM * BK * 2) + buf * (BN * BK); };

    // ---- B async staging: inst j of wave w covers rows [r*8, r*8+8), r=w*8+j.
    // Lane l -> row r*8 + (l>>3), slot l&7 holds chunk c=(l&7)^((l>>3)&7).
    const int brow_l = l >> 3;
    const int bc     = (l & 7) ^ (brow_l & 7);

    auto stageB = [&](int buf, int k0) {
        __bf16* B = bufB(buf);
        #pragma unroll
        for (int j = 0; j < 8; ++j) {
            const int r   = w * 8 + j;
            const int row = r * 8 + brow_l;
            const __bf16* g = WT + (size_t)row * D_DIM + k0 + bc * 8;
            async16(g, B + r * 512);
        }
    };

    // ---- A staging: thread t -> row t>>2 (64 rows), 16 f32 at chunk-pair
    // c=t&3 -> bf16 chunks 2c, 2c+1, stored swizzled: pos = chunk ^ (row&7).
    const int arow = tid >> 2;
    const int ac   = tid & 3;
    const float* agp = A + (size_t)(m0 + arow) * D_DIM + ac * 16;
    const int p0 = ((2 * ac)     ^ (arow & 7)) * 8;
    const int p1 = ((2 * ac + 1) ^ (arow & 7)) * 8;

    float4 fa[4];
    auto loadA = [&](int k0) {
        #pragma unroll
        for (int i = 0; i < 4; ++i) fa[i] = *(const float4*)(agp + k0 + 4 * i);
    };
    auto writeA = [&](int buf) {
        bf16x8 v0, v1;
        v0[0] = (__bf16)fa[0].x; v0[1] = (__bf16)fa[0].y; v0[2] = (__bf16)fa[0].z; v0[3] = (__bf16)fa[0].w;
        v0[4] = (__bf16)fa[1].x; v0[5] = (__bf16)fa[1].y; v0[6] = (__bf16)fa[1].z; v0[7] = (__bf16)fa[1].w;
        v1[0] = (__bf16)fa[2].x; v1[1] = (__bf16)fa[2].y; v1[2] = (__bf16)fa[2].z; v1[3] = (__bf16)fa[2].w;
        v1[4] = (__bf16)fa[3].x; v1[5] = (__bf16)fa[3].y; v1[6] = (__bf16)fa[3].z; v1[7] = (__bf16)fa[3].w;
        __bf16* Ab = bufA(buf) + arow * BK;
        *(bf16x8*)(Ab + p0) = v0;
        *(bf16x8*)(Ab + p1) = v1;
    };

    f32x4 acc[4][4] = {};

    auto compute = [&](int buf) {
        const __bf16* Ab = bufA(buf);
        const __bf16* Bb = bufB(buf);
        #pragma unroll
        for (int kh = 0; kh < 2; ++kh) {
            const int pos = ((kh * 4 + q) ^ (lm & 7)) * 8;
            bf16x8 af[4], bfr[4];
            #pragma unroll
            for (int mi = 0; mi < 4; ++mi)
                af[mi] = *(const bf16x8*)(Ab + (mi * 16 + lm) * BK + pos);
            #pragma unroll
            for (int ni = 0; ni < 4; ++ni)
                bfr[ni] = *(const bf16x8*)(Bb + (w * 64 + ni * 16 + lm) * BK + pos);
            #pragma unroll
            for (int mi = 0; mi < 4; ++mi)
                #pragma unroll
                for (int ni = 0; ni < 4; ++ni)
                    acc[mi][ni] = __builtin_amdgcn_mfma_f32_16x16x32_bf16(
                        af[mi], bfr[ni], acc[mi][ni], 0, 0, 0);
        }
    };

    // ---- pipeline: 16 K-steps, buffers alternate 0,1,0,1,...
    loadA(0);
    stageB(0, 0);
    writeA(0);
    __syncthreads();

    #pragma unroll 1
    for (int p = 0; p < 7; ++p) {
        const int k1 = (2 * p + 1) * BK, k2 = (2 * p + 2) * BK;
        loadA(k1); stageB(1, k1);
        __builtin_amdgcn_sched_barrier(0);
        compute(0);
        __builtin_amdgcn_sched_barrier(0);
        writeA(1);
        __syncthreads();
        loadA(k2); stageB(0, k2);
        __builtin_amdgcn_sched_barrier(0);
        compute(1);
        __builtin_amdgcn_sched_barrier(0);
        writeA(0);
        __syncthreads();
    }
    {   // step 14 (buf 0) while staging step 15 (buf 1)
        const int k1 = 15 * BK;
        loadA(k1); stageB(1, k1);
        __builtin_amdgcn_sched_barrier(0);
        compute(0);
        __builtin_amdgcn_sched_barrier(0);
        writeA(1);
        __syncthreads();
    }
    compute(1);

    // ---- fused epilogue ------------------------------------------------------
    __syncthreads();                       // all waves done reading As/Bs
    float* hs = (float*)smem;              // 64 x HS f32 overlay (66.6 KB < 80 KB)

    if (tid < 64) { int c = cnt[m0 + tid]; s_cnt[tid] = c < CAP ? c : CAP; }

    // D layout: row = mi*16 + q*4 + r, col = w*64 + ni*16 + lm
    #pragma unroll
    for (int ni = 0; ni < 4; ++ni) {
        const int col = w * 64 + ni * 16 + lm;
        const float bv = bias[col];
        #pragma unroll
        for (int mi = 0; mi < 4; ++mi) {
            const int rbase = mi * 16 + q * 4;
            #pragma unroll
            for (int r = 0; r < 4; ++r)
                hs[(rbase + r) * HS + col] = acc[mi][ni][r] + bv;
        }
    }
    __syncthreads();
    if (tid == 0) {
        int a = 0;
        #pragma unroll 1
        for (int i = 0; i < 64; ++i) { s_off[i] = a; a += s_cnt[i]; }
        s_off[64] = a;
    }
    __syncthreads();
    if (tid < 64) {
        const int o = s_off[tid], c = s_cnt[tid];
        const int* bk = bucket + (size_t)(m0 + tid) * CAP;
        for (int k = 0; k < c; ++k)
            elist[o + k] = (tid << 15) | (bk[k] & 0x7fff);
    }
    __syncthreads();

    const int E   = s_off[64];
    const int grp = tid >> 6;
    const int gl  = tid & 63;
    #pragma unroll 1
    for (int j = grp; j < E; j += 4) {
        const int ent  = elist[j];
        const int rl   = ent >> 15;
        const int code = ent & 0x7fff;
        const int qq   = code >> 2;
        const int st   = (code >> 1) & 1;
        const int hf   = code & 1;
        const float4 v = *(const float4*)&hs[rl * HS + gl * 4];
        *(float4*)(out + (size_t)st * (NQ_ * 512) + (size_t)qq * 512 + hf * 256 + gl * 4) = v;
    }
}

// ---------------- launch ------------------------------------------------------
extern "C" void kernel_launch(void* const* d_in, const int* in_sizes, int n_in,
                              void* d_out, int out_size, void* d_ws, size_t ws_size,
                              hipStream_t stream) {
    const float* A    = (const float*)d_in[1];
    const int*   s1   = (const int*)  d_in[2];
    const int*   e1   = (const int*)  d_in[3];
    const int*   qb   = (const int*)  d_in[4];
    const int*   s2   = (const int*)  d_in[5];
    const int*   e2   = (const int*)  d_in[6];
    const float* W    = (const float*)d_in[7];
    const float* bias = (const float*)d_in[8];
    float*       out  = (float*)d_out;

    __bf16* WT     = (__bf16*)d_ws;                                   // 512 KB
    int*    cnt    = (int*)((char*)d_ws + (1 << 20));                 // 64 KB
    int*    bucket = (int*)((char*)d_ws + (1 << 20) + (1 << 16));     // 2 MB

    wt_kernel  <<<dim3(32, 8), dim3(32, 32), 0, stream>>>(W, WT, cnt);
    index_zero <<<dim3(NQ_ / 256), dim3(256), 0, stream>>>(s1, e1, s2, e2, qb, cnt, bucket, out);
    gemm_kernel<<<dim3(M_TOT / BM), dim3(256), 0, stream>>>(A, WT, bias, cnt, bucket, out);
}